// Round 1
// baseline (165.710 us; speedup 1.0000x reference)
//
#include <hip/hip_runtime.h>
#include <math.h>

#define N 1024
#define DIM 128
#define LAMB 0.9f
#define INV2SIG2 (1.0f / 450.0f)   // 0.5 / sigma^2, sigma=15

typedef short v8s __attribute__((ext_vector_type(8)));
typedef float v4f __attribute__((ext_vector_type(4)));

__device__ __forceinline__ unsigned short f2bf(float x) {   // RNE float->bf16
    unsigned int u = __float_as_uint(x);
    u += 0x7FFFu + ((u >> 16) & 1u);
    return (unsigned short)(u >> 16);
}
__device__ __forceinline__ float bf2f(unsigned short h) {
    return __uint_as_float(((unsigned int)h) << 16);
}
__device__ __forceinline__ v8s cvt8(const float* p) {      // 8 fp32 -> v8s bf16
    v8s r;
    #pragma unroll
    for (int i = 0; i < 8; ++i) r[i] = (short)f2bf(p[i]);
    return r;
}

// Grid barrier over 256 co-resident blocks. Monotonic counter (no reset races),
// one device-scope RMW arrival per block; poll is a relaxed agent-scope LOAD with
// s_sleep backoff (NOT an RMW storm — that was the prior session's 15us/barrier
// mistake). Release: syncthreads drains each wave's stores, t0's threadfence does
// the bulk L2 writeback. Acquire: threadfence after observing target invalidates
// stale L1/L2 lines before any thread reads cross-block data.
__device__ __forceinline__ void gridbar(unsigned int* bar, unsigned int target) {
    __syncthreads();
    if (threadIdx.x == 0) {
        __threadfence();
        unsigned int v = atomicAdd(bar, 1u) + 1u;
        while (v < target) {
            __builtin_amdgcn_s_sleep(8);
            v = __hip_atomic_load(bar, __ATOMIC_RELAXED, __HIP_MEMORY_SCOPE_AGENT);
        }
        __threadfence();
    }
    __syncthreads();
}

// ---- mv iteration: v[r] = P0[r] + (lamb/total[r]) * zscale * (Bu[r,:] . z) ----
__device__ __forceinline__ void mv_iter(
    const unsigned short* __restrict__ M, const float* __restrict__ A0,
    const float* __restrict__ total, const float* __restrict__ z,
    float* __restrict__ v, int first, int wave, int lane)
{
    const int r = blockIdx.x * 4 + wave;
    const float r0s = 1.0f / fmaxf(total[0], 1e-10f);
    const float rscale = (r == 0) ? 0.f : LAMB / fmaxf(total[r], 1e-10f);
    const float p0r    = (r == 0) ? 0.f : A0[r] * r0s;
    const float zscale = first ? r0s : 1.0f;

    const uint4* m4 = (const uint4*)(M + r * N + lane * 16);
    const float4* z4 = (const float4*)(z + lane * 16);
    uint4 ma = m4[0], mb = m4[1];
    float4 z0 = z4[0], z1 = z4[1], z2 = z4[2], z3 = z4[3];
    float acc = 0.f;
    acc += bf2f((unsigned short)(ma.x)) * z0.x + bf2f((unsigned short)(ma.x >> 16)) * z0.y;
    acc += bf2f((unsigned short)(ma.y)) * z0.z + bf2f((unsigned short)(ma.y >> 16)) * z0.w;
    acc += bf2f((unsigned short)(ma.z)) * z1.x + bf2f((unsigned short)(ma.z >> 16)) * z1.y;
    acc += bf2f((unsigned short)(ma.w)) * z1.z + bf2f((unsigned short)(ma.w >> 16)) * z1.w;
    acc += bf2f((unsigned short)(mb.x)) * z2.x + bf2f((unsigned short)(mb.x >> 16)) * z2.y;
    acc += bf2f((unsigned short)(mb.y)) * z2.z + bf2f((unsigned short)(mb.y >> 16)) * z2.w;
    acc += bf2f((unsigned short)(mb.z)) * z3.x + bf2f((unsigned short)(mb.z >> 16)) * z3.y;
    acc += bf2f((unsigned short)(mb.w)) * z3.z + bf2f((unsigned short)(mb.w >> 16)) * z3.w;
    #pragma unroll
    for (int off = 32; off >= 1; off >>= 1) acc += __shfl_xor(acc, off, 64);
    if (lane == 0) v[r] = p0r + rscale * zscale * acc;
}

// ---------------- single fused kernel: compose | gemm2 | aff | mv x3 | epilogue ----
__global__ __launch_bounds__(256) void k_mega(
    const float* __restrict__ f,
    const float* __restrict__ w1, const float* __restrict__ b1,
    const float* __restrict__ w2, const float* __restrict__ b2,
    const float* __restrict__ w3, const float* __restrict__ b3,
    const float* __restrict__ w4, const float* __restrict__ b4,
    float* __restrict__ ws, float* __restrict__ out)
{
    // float-unit workspace offsets (meta region ws+33024..36352 pre-zeroed by memset)
    float* Wboth = ws;                                    // 32768
    float* bboth = ws + 32768;                            // 256
    float* fn2   = ws + 33024;                            // 1024
    float* mag   = ws + 34048;                            // 1024
    float* total = ws + 35072;                            // 1024
    unsigned int* donecnt = (unsigned int*)(ws + 36096);
    unsigned int* bar     = (unsigned int*)(ws + 36097);
    float* A0  = ws + 36352;                              // 1024
    float* zb0 = ws + 37376;                              // 1024
    float* zb1 = ws + 38400;                              // 1024
    float* zb2 = ws + 39424;                              // 1024
    unsigned short* xb = (unsigned short*)(ws + 40448);   // 1024x128 bf16
    unsigned short* Bu = (unsigned short*)(ws + 105984);  // 1024x1024 bf16

    __shared__ float u0[2][128];
    __shared__ float u1[2][128];
    __shared__ float red4[4];
    __shared__ float bvalS;
    __shared__ float ush[1024];
    __shared__ int winner;

    const int b = blockIdx.x, t = threadIdx.x;
    const int wave = t >> 6, lane = t & 63;
    const int l15 = lane & 15, quad = lane >> 4;

    // ======== stage A: weight/bias composition (blocks 0..128; 129+ idle) ========
    if (b < 64) {                       // G rows 2b, 2b+1
        const int h = t >> 7, j = t & 127;
        const int i = 2 * b + h;
        float acc = 0.f;
        #pragma unroll 8
        for (int k = 0; k < 128; ++k) acc += w4[i * 128 + k] * w3[k * 128 + j];
        u0[h][j] = acc;
        __syncthreads();
        float acc2 = 0.f;
        #pragma unroll 8
        for (int l = 0; l < 128; ++l) acc2 += u0[h][l] * w2[l * 128 + j];
        Wboth[i * 128 + j] = acc2;
    } else if (b < 128) {               // X rows
        const int h = t >> 7, j = t & 127;
        const int i = 2 * (b - 64) + h;
        float acc = 0.f;
        #pragma unroll 8
        for (int k = 0; k < 128; ++k) acc += w1[i * 128 + k] * w4[k * 128 + j];
        u0[h][j] = acc;
        __syncthreads();
        float acc2 = 0.f;
        #pragma unroll 8
        for (int k = 0; k < 128; ++k) acc2 += u0[h][k] * w3[k * 128 + j];
        u1[h][j] = acc2;
        __syncthreads();
        float acc3 = 0.f;
        #pragma unroll 8
        for (int l = 0; l < 128; ++l) acc3 += u1[h][l] * w2[l * 128 + j];
        Wboth[(128 + i) * 128 + j] = acc3;
    } else if (b == 128) {              // bias chain (3 sequential vec-mats)
        if (t < 128) {
            float a3 = b3[t];
            #pragma unroll 8
            for (int k = 0; k < 128; ++k) a3 += w3[t * 128 + k] * b2[k];
            u0[0][t] = a3;
        }
        __syncthreads();
        if (t < 128) {
            float a4 = b4[t];
            #pragma unroll 8
            for (int k = 0; k < 128; ++k) a4 += w4[t * 128 + k] * u0[0][k];
            u1[0][t] = a4;
            bboth[t] = a4;              // bg
        }
        __syncthreads();
        if (t < 128) {
            float ax = b1[t];
            #pragma unroll 8
            for (int k = 0; k < 128; ++k) ax += w1[t * 128 + k] * u1[0][k];
            bboth[128 + t] = ax;        // bx
        }
    }
    gridbar(bar, 256);

    // ======== stage B: Y = f @ Wb^T + bboth -> xb (bf16), fn2, mag ========
    {
        const int i0 = (b >> 4) * 64;       // 16 row-tiles of 64
        const int j0 = (b & 15) * 16;       // 16 col-tiles of 16 (over 256 outputs)
        const int ri = i0 + wave * 16;
        const float* ap = f     + (ri + l15) * 128 + quad * 8;
        const float* bp = Wboth + (j0 + l15) * 128 + quad * 8;
        v4f acc = {0.f, 0.f, 0.f, 0.f};
        #pragma unroll
        for (int kc = 0; kc < 4; ++kc) {
            v8s a   = cvt8(ap + kc * 32);
            v8s bbv = cvt8(bp + kc * 32);
            acc = __builtin_amdgcn_mfma_f32_16x16x32_bf16(a, bbv, acc, 0, 0, 0);
        }
        const float bias = bboth[j0 + l15];
        const bool isx = (j0 >= 128);
        float sq[4];
        #pragma unroll
        for (int reg = 0; reg < 4; ++reg) {
            float yv = acc[reg] + bias;
            sq[reg] = yv * yv;
            if (isx) xb[(ri + quad * 4 + reg) * DIM + (j0 - 128) + l15] = f2bf(yv);
        }
        #pragma unroll
        for (int reg = 0; reg < 4; ++reg) {
            float ss = sq[reg];
            ss += __shfl_xor(ss, 1, 64); ss += __shfl_xor(ss, 2, 64);
            ss += __shfl_xor(ss, 4, 64); ss += __shfl_xor(ss, 8, 64);
            if (l15 == 0)
                atomicAdd((isx ? mag : fn2) + (ri + quad * 4 + reg), ss);
        }
    }
    gridbar(bar, 512);

    // ======== stage C: affinity -> Bu (unscaled bf16), totals, A0 ========
    {
        const int slab = b >> 2;            // rows slab*16..+16
        const int qtr  = b & 3;             // j-quarter (256 cols)
        const int i0 = slab * 16;

        const unsigned short* ap = xb + (i0 + l15) * DIM + quad * 8;
        v8s afr[4];
        #pragma unroll
        for (int kc = 0; kc < 4; ++kc) afr[kc] = *(const v8s*)(ap + kc * 32);

        float rowsum[4] = {0.f, 0.f, 0.f, 0.f};
        #pragma unroll
        for (int s = 0; s < 4; ++s) {
            const int j0 = (qtr * 16 + wave * 4 + s) * 16;
            const unsigned short* bp = xb + (j0 + l15) * DIM + quad * 8;
            v4f acc = {0.f, 0.f, 0.f, 0.f};
            #pragma unroll
            for (int kc = 0; kc < 4; ++kc)
                acc = __builtin_amdgcn_mfma_f32_16x16x32_bf16(
                          afr[kc], *(const v8s*)(bp + kc * 32), acc, 0, 0, 0);
            const int gj = j0 + l15;
            const float rm = 1.0f / mag[gj];
            const float fj = fn2[gj] * INV2SIG2;
            #pragma unroll
            for (int reg = 0; reg < 4; ++reg) {
                const int gi = i0 + quad * 4 + reg;
                float Sv = acc[reg] * rm - 1.0f;
                float a = (gi == gj) ? 0.f : __expf(-(Sv * Sv) * fj);
                Bu[gi * N + gj] = f2bf(a);
                rowsum[reg] += a;
                if (gi == 0) A0[gj] = a;    // fp32 row 0 for P0
            }
        }
        #pragma unroll
        for (int reg = 0; reg < 4; ++reg) {
            float ss = rowsum[reg];
            ss += __shfl_xor(ss, 1, 64); ss += __shfl_xor(ss, 2, 64);
            ss += __shfl_xor(ss, 4, 64); ss += __shfl_xor(ss, 8, 64);
            if (l15 == 0) atomicAdd(&total[i0 + quad * 4 + reg], ss);
        }
    }
    gridbar(bar, 768);

    // ======== stages D/E/F: Neumann chain, 3 matvecs ========
    mv_iter(Bu, A0, total, A0,  zb0, 1, wave, lane);
    gridbar(bar, 1024);
    mv_iter(Bu, A0, total, zb0, zb1, 0, wave, lane);
    gridbar(bar, 1280);
    mv_iter(Bu, A0, total, zb1, zb2, 0, wave, lane);

    // last-block-done: one release RMW per block; winner runs the epilogue.
    __syncthreads();
    if (t == 0) {
        __threadfence();
        unsigned int old = atomicAdd(donecnt, 1u);
        winner = (old == 255u) ? 1 : 0;
        if (winner) __threadfence();
    }
    __syncthreads();
    if (!winner) return;

    // ---- 256-thread Aitken + softmax epilogue: zM = zb2, zM1 = zb1, zM2 = zb0 ----
    const float* zM  = zb2;
    const float* zM1 = zb1;
    const float* zM2 = zb0;
    float av[4], d1v[4];
    float s12 = 0.f, s22 = 0.f;
    #pragma unroll
    for (int k = 0; k < 4; ++k) {
        const int e = t + 256 * k;
        av[k] = zM[e];
        float bb = zM1[e], cc = zM2[e];
        d1v[k] = av[k] - bb;
        float d2 = bb - cc;
        s12 += d1v[k] * d2;
        s22 += d2 * d2;
    }
    #pragma unroll
    for (int off = 32; off >= 1; off >>= 1) s12 += __shfl_down(s12, off, 64);
    if (lane == 0) red4[wave] = s12;
    __syncthreads();
    if (t == 0) bvalS = red4[0] + red4[1] + red4[2] + red4[3];
    __syncthreads();
    const float dot12 = bvalS;
    __syncthreads();
    #pragma unroll
    for (int off = 32; off >= 1; off >>= 1) s22 += __shfl_down(s22, off, 64);
    if (lane == 0) red4[wave] = s22;
    __syncthreads();
    if (t == 0) bvalS = red4[0] + red4[1] + red4[2] + red4[3];
    __syncthreads();
    const float dot22 = bvalS;
    __syncthreads();

    float lam = dot12 / fmaxf(dot22, 1e-30f);
    lam = fminf(fmaxf(lam, 0.0f), 0.95f);
    const float coef = lam / (1.0f - lam);
    #pragma unroll
    for (int k = 0; k < 4; ++k) ush[t + 256 * k] = av[k] + coef * d1v[k];
    __syncthreads();

    float Pv[4];
    float ps = 0.f;
    #pragma unroll
    for (int k = 0; k < 4; ++k) {
        const int e = t + 256 * k;
        Pv[k] = (e >= 1) ? 0.1f * ush[e] : 0.f;
        ps += Pv[k];
    }
    #pragma unroll
    for (int off = 32; off >= 1; off >>= 1) ps += __shfl_down(ps, off, 64);
    if (lane == 0) red4[wave] = ps;
    __syncthreads();
    if (t == 0) bvalS = (red4[0] + red4[1] + red4[2] + red4[3]) / 1023.0f;
    __syncthreads();
    const float mean = bvalS;
    __syncthreads();

    float mx = 0.f;   // relu'd values >= 0
    #pragma unroll
    for (int k = 0; k < 4; ++k) {
        const int e = t + 256 * k;
        if (e >= 1) {
            Pv[k] = fmaxf(Pv[k] - mean, 0.f) * 100.f;
            mx = fmaxf(mx, Pv[k]);
        }
    }
    #pragma unroll
    for (int off = 32; off >= 1; off >>= 1) mx = fmaxf(mx, __shfl_down(mx, off, 64));
    if (lane == 0) red4[wave] = mx;
    __syncthreads();
    if (t == 0) bvalS = fmaxf(fmaxf(red4[0], red4[1]), fmaxf(red4[2], red4[3]));
    __syncthreads();
    const float gmax = bvalS;
    __syncthreads();

    float Ev[4];
    float es = 0.f;
    #pragma unroll
    for (int k = 0; k < 4; ++k) {
        const int e = t + 256 * k;
        Ev[k] = (e >= 1) ? expf(Pv[k] - gmax) : 0.f;
        es += Ev[k];
    }
    #pragma unroll
    for (int off = 32; off >= 1; off >>= 1) es += __shfl_down(es, off, 64);
    if (lane == 0) red4[wave] = es;
    __syncthreads();
    if (t == 0) bvalS = red4[0] + red4[1] + red4[2] + red4[3];
    __syncthreads();
    const float esum = bvalS;
    #pragma unroll
    for (int k = 0; k < 4; ++k) {
        const int e = t + 256 * k;
        if (e >= 1) out[e - 1] = Ev[k] / esum;
    }
}

extern "C" void kernel_launch(void* const* d_in, const int* in_sizes, int n_in,
                              void* d_out, int out_size, void* d_ws, size_t ws_size,
                              hipStream_t stream) {
    const float* f  = (const float*)d_in[0];
    const float* w1 = (const float*)d_in[1];
    const float* b1 = (const float*)d_in[2];
    const float* w2 = (const float*)d_in[3];
    const float* b2 = (const float*)d_in[4];
    const float* w3 = (const float*)d_in[5];
    const float* b3 = (const float*)d_in[6];
    const float* w4 = (const float*)d_in[7];
    const float* b4 = (const float*)d_in[8];
    float* ws = (float*)d_ws;

    // zero meta region: fn2/mag/total (atomic accumulators) + donecnt + barrier
    // counter. Must be a stream op (graph replays re-poison the workspace, and the
    // barrier counter cannot zero itself).  floats 33024..36352 -> 13312 bytes.
    hipMemsetAsync((char*)d_ws + 33024 * 4, 0, 3328 * 4, stream);

    k_mega<<<256, 256, 0, stream>>>(f, w1, b1, w2, b2, w3, b3, w4, b4,
                                    ws, (float*)d_out);
}

// Round 3
// 120.440 us; speedup vs baseline: 1.3759x; 1.3759x over previous
//
#include <hip/hip_runtime.h>
#include <math.h>

#define N 1024
#define DIM 128
#define LAMB 0.9f
#define INV2SIG2 (1.0f / 450.0f)   // 0.5 / sigma^2, sigma=15

typedef short v8s __attribute__((ext_vector_type(8)));
typedef float v4f __attribute__((ext_vector_type(4)));

__device__ __forceinline__ unsigned short f2bf(float x) {   // RNE float->bf16
    unsigned int u = __float_as_uint(x);
    u += 0x7FFFu + ((u >> 16) & 1u);
    return (unsigned short)(u >> 16);
}
__device__ __forceinline__ float bf2f(unsigned short h) {
    return __uint_as_float(((unsigned int)h) << 16);
}
__device__ __forceinline__ v8s cvt8(const float* p) {      // 8 fp32 -> v8s bf16
    v8s r;
    #pragma unroll
    for (int i = 0; i < 8; ++i) r[i] = (short)f2bf(p[i]);
    return r;
}

// Device-coherent (write-through to coherence point) stores. sc0 sc1 on gfx950
// = agent-scope coherent: the store is visible device-wide once vmcnt retires,
// so grid barriers need NO buffer_wbl2/buffer_inv (round-1's ~10us/barrier cost).
__device__ __forceinline__ void st_dc_f32(float* p, float v) {
    asm volatile("global_store_dword %0, %1, off sc0 sc1" :: "v"(p), "v"(v) : "memory");
}
__device__ __forceinline__ void st_dc_u16(unsigned short* p, unsigned short v) {
    unsigned int vv = v;
    asm volatile("global_store_short %0, %1, off sc0 sc1" :: "v"(p), "v"(vv) : "memory");
}

// Fence-free grid barrier over 256 co-resident blocks. All cross-stage data was
// stored with sc0|sc1 (device-coherent), so after each thread drains vmcnt the
// data is globally visible: arrival is one device-scope RMW, wait is a relaxed
// agent-scope load with s_sleep backoff. No threadfence, no L2 wb/inv.
__device__ __forceinline__ void gridbar(unsigned int* bar, unsigned int target) {
    asm volatile("s_waitcnt vmcnt(0)" ::: "memory");   // asm stores drained
    __syncthreads();
    if (threadIdx.x == 0) {
        unsigned int v = atomicAdd(bar, 1u) + 1u;
        while (v < target) {
            __builtin_amdgcn_s_sleep(8);
            v = __hip_atomic_load(bar, __ATOMIC_RELAXED, __HIP_MEMORY_SCOPE_AGENT);
        }
    }
    __syncthreads();
}

// ---- mv iteration: v[r] = P0[r] + (lamb/total[r]) * zscale * (Bu[r,:] . z) ----
__device__ __forceinline__ void mv_iter(
    const unsigned short* __restrict__ M, const float* __restrict__ A0,
    const float* __restrict__ total, const float* __restrict__ z,
    float* __restrict__ v, int first, int wave, int lane)
{
    const int r = blockIdx.x * 4 + wave;
    const float r0s = 1.0f / fmaxf(total[0], 1e-10f);
    const float rscale = (r == 0) ? 0.f : LAMB / fmaxf(total[r], 1e-10f);
    const float p0r    = (r == 0) ? 0.f : A0[r] * r0s;
    const float zscale = first ? r0s : 1.0f;

    const uint4* m4 = (const uint4*)(M + r * N + lane * 16);
    const float4* z4 = (const float4*)(z + lane * 16);
    uint4 ma = m4[0], mb = m4[1];
    float4 z0 = z4[0], z1 = z4[1], z2 = z4[2], z3 = z4[3];
    float acc = 0.f;
    acc += bf2f((unsigned short)(ma.x)) * z0.x + bf2f((unsigned short)(ma.x >> 16)) * z0.y;
    acc += bf2f((unsigned short)(ma.y)) * z0.z + bf2f((unsigned short)(ma.y >> 16)) * z0.w;
    acc += bf2f((unsigned short)(ma.z)) * z1.x + bf2f((unsigned short)(ma.z >> 16)) * z1.y;
    acc += bf2f((unsigned short)(ma.w)) * z1.z + bf2f((unsigned short)(ma.w >> 16)) * z1.w;
    acc += bf2f((unsigned short)(mb.x)) * z2.x + bf2f((unsigned short)(mb.x >> 16)) * z2.y;
    acc += bf2f((unsigned short)(mb.y)) * z2.z + bf2f((unsigned short)(mb.y >> 16)) * z2.w;
    acc += bf2f((unsigned short)(mb.z)) * z3.x + bf2f((unsigned short)(mb.z >> 16)) * z3.y;
    acc += bf2f((unsigned short)(mb.w)) * z3.z + bf2f((unsigned short)(mb.w >> 16)) * z3.w;
    #pragma unroll
    for (int off = 32; off >= 1; off >>= 1) acc += __shfl_xor(acc, off, 64);
    if (lane == 0) st_dc_f32(&v[r], p0r + rscale * zscale * acc);
}

// ---------------- single fused kernel: compose | gemm2 | aff | mv x3 | epilogue ----
__global__ __launch_bounds__(256) void k_mega(
    const float* __restrict__ f,
    const float* __restrict__ w1, const float* __restrict__ b1,
    const float* __restrict__ w2, const float* __restrict__ b2,
    const float* __restrict__ w3, const float* __restrict__ b3,
    const float* __restrict__ w4, const float* __restrict__ b4,
    float* __restrict__ ws, float* __restrict__ out)
{
    // float-unit workspace offsets (only bar/donecnt pre-zeroed by 8B memset)
    float* Wboth = ws;                                    // 32768
    float* bboth = ws + 32768;                            // 256
    float* fn2   = ws + 33024;                            // 1024 (zeroed in stage A)
    float* mag   = ws + 34048;                            // 1024 (zeroed in stage A)
    float* total = ws + 35072;                            // 1024 (zeroed in stage A)
    unsigned int* donecnt = (unsigned int*)(ws + 36096);
    unsigned int* bar     = (unsigned int*)(ws + 36097);
    float* A0  = ws + 36352;                              // 1024
    float* zb0 = ws + 37376;                              // 1024
    float* zb1 = ws + 38400;                              // 1024
    float* zb2 = ws + 39424;                              // 1024
    unsigned short* xb = (unsigned short*)(ws + 40448);   // 1024x128 bf16
    unsigned short* Bu = (unsigned short*)(ws + 105984);  // 1024x1024 bf16

    __shared__ float u0[2][128];
    __shared__ float u1[2][128];
    __shared__ float red4[4];
    __shared__ float bvalS;
    __shared__ float ush[1024];
    __shared__ int winner;

    const int b = blockIdx.x, t = threadIdx.x;
    const int wave = t >> 6, lane = t & 63;
    const int l15 = lane & 15, quad = lane >> 4;

    // ======== stage A: weight/bias composition; idle blocks zero accumulators ====
    if (b < 64) {                       // G rows 2b, 2b+1
        const int h = t >> 7, j = t & 127;
        const int i = 2 * b + h;
        float acc = 0.f;
        #pragma unroll 8
        for (int k = 0; k < 128; ++k) acc += w4[i * 128 + k] * w3[k * 128 + j];
        u0[h][j] = acc;
        __syncthreads();
        float acc2 = 0.f;
        #pragma unroll 8
        for (int l = 0; l < 128; ++l) acc2 += u0[h][l] * w2[l * 128 + j];
        st_dc_f32(&Wboth[i * 128 + j], acc2);
    } else if (b < 128) {               // X rows
        const int h = t >> 7, j = t & 127;
        const int i = 2 * (b - 64) + h;
        float acc = 0.f;
        #pragma unroll 8
        for (int k = 0; k < 128; ++k) acc += w1[i * 128 + k] * w4[k * 128 + j];
        u0[h][j] = acc;
        __syncthreads();
        float acc2 = 0.f;
        #pragma unroll 8
        for (int k = 0; k < 128; ++k) acc2 += u0[h][k] * w3[k * 128 + j];
        u1[h][j] = acc2;
        __syncthreads();
        float acc3 = 0.f;
        #pragma unroll 8
        for (int l = 0; l < 128; ++l) acc3 += u1[h][l] * w2[l * 128 + j];
        st_dc_f32(&Wboth[(128 + i) * 128 + j], acc3);
    } else if (b == 128) {              // bias chain (3 sequential vec-mats)
        if (t < 128) {
            float a3 = b3[t];
            #pragma unroll 8
            for (int k = 0; k < 128; ++k) a3 += w3[t * 128 + k] * b2[k];
            u0[0][t] = a3;
        }
        __syncthreads();
        if (t < 128) {
            float a4 = b4[t];
            #pragma unroll 8
            for (int k = 0; k < 128; ++k) a4 += w4[t * 128 + k] * u0[0][k];
            u1[0][t] = a4;
            st_dc_f32(&bboth[t], a4);   // bg
        }
        __syncthreads();
        if (t < 128) {
            float ax = b1[t];
            #pragma unroll 8
            for (int k = 0; k < 128; ++k) ax += w1[t * 128 + k] * u1[0][k];
            st_dc_f32(&bboth[128 + t], ax);  // bx
        }
    } else if (b >= 129 && b < 141) {   // zero fn2/mag/total (3072 contiguous)
        st_dc_f32(&fn2[(b - 129) * 256 + t], 0.f);
    }
    gridbar(bar, 256);

    // ======== stage B: Y = f @ Wb^T + bboth -> xb (bf16), fn2, mag ========
    {
        const int i0 = (b >> 4) * 64;       // 16 row-tiles of 64
        const int j0 = (b & 15) * 16;       // 16 col-tiles of 16 (over 256 outputs)
        const int ri = i0 + wave * 16;
        const float* ap = f     + (ri + l15) * 128 + quad * 8;
        const float* bp = Wboth + (j0 + l15) * 128 + quad * 8;
        v4f acc = {0.f, 0.f, 0.f, 0.f};
        #pragma unroll
        for (int kc = 0; kc < 4; ++kc) {
            v8s a   = cvt8(ap + kc * 32);
            v8s bbv = cvt8(bp + kc * 32);
            acc = __builtin_amdgcn_mfma_f32_16x16x32_bf16(a, bbv, acc, 0, 0, 0);
        }
        const float bias = bboth[j0 + l15];
        const bool isx = (j0 >= 128);
        float sq[4];
        #pragma unroll
        for (int reg = 0; reg < 4; ++reg) {
            float yv = acc[reg] + bias;
            sq[reg] = yv * yv;
            if (isx) st_dc_u16(&xb[(ri + quad * 4 + reg) * DIM + (j0 - 128) + l15],
                               f2bf(yv));
        }
        #pragma unroll
        for (int reg = 0; reg < 4; ++reg) {
            float ss = sq[reg];
            ss += __shfl_xor(ss, 1, 64); ss += __shfl_xor(ss, 2, 64);
            ss += __shfl_xor(ss, 4, 64); ss += __shfl_xor(ss, 8, 64);
            if (l15 == 0)
                atomicAdd((isx ? mag : fn2) + (ri + quad * 4 + reg), ss);
        }
    }
    gridbar(bar, 512);

    // ======== stage C: affinity -> Bu (unscaled bf16), totals, A0 ========
    {
        const int slab = b >> 2;            // rows slab*16..+16
        const int qtr  = b & 3;             // j-quarter (256 cols)
        const int i0 = slab * 16;

        const unsigned short* ap = xb + (i0 + l15) * DIM + quad * 8;
        v8s afr[4];
        #pragma unroll
        for (int kc = 0; kc < 4; ++kc) afr[kc] = *(const v8s*)(ap + kc * 32);

        float rowsum[4] = {0.f, 0.f, 0.f, 0.f};
        #pragma unroll
        for (int s = 0; s < 4; ++s) {
            const int j0 = (qtr * 16 + wave * 4 + s) * 16;
            const unsigned short* bp = xb + (j0 + l15) * DIM + quad * 8;
            v4f acc = {0.f, 0.f, 0.f, 0.f};
            #pragma unroll
            for (int kc = 0; kc < 4; ++kc)
                acc = __builtin_amdgcn_mfma_f32_16x16x32_bf16(
                          afr[kc], *(const v8s*)(bp + kc * 32), acc, 0, 0, 0);
            const int gj = j0 + l15;
            const float rm = 1.0f / mag[gj];
            const float fj = fn2[gj] * INV2SIG2;
            #pragma unroll
            for (int reg = 0; reg < 4; ++reg) {
                const int gi = i0 + quad * 4 + reg;
                float Sv = acc[reg] * rm - 1.0f;
                float a = (gi == gj) ? 0.f : __expf(-(Sv * Sv) * fj);
                st_dc_u16(&Bu[gi * N + gj], f2bf(a));
                rowsum[reg] += a;
                if (gi == 0) st_dc_f32(&A0[gj], a);   // fp32 row 0 for P0
            }
        }
        #pragma unroll
        for (int reg = 0; reg < 4; ++reg) {
            float ss = rowsum[reg];
            ss += __shfl_xor(ss, 1, 64); ss += __shfl_xor(ss, 2, 64);
            ss += __shfl_xor(ss, 4, 64); ss += __shfl_xor(ss, 8, 64);
            if (l15 == 0) atomicAdd(&total[i0 + quad * 4 + reg], ss);
        }
    }
    gridbar(bar, 768);

    // ======== stages D/E/F: Neumann chain, 3 matvecs ========
    mv_iter(Bu, A0, total, A0,  zb0, 1, wave, lane);
    gridbar(bar, 1024);
    mv_iter(Bu, A0, total, zb0, zb1, 0, wave, lane);
    gridbar(bar, 1280);
    mv_iter(Bu, A0, total, zb1, zb2, 0, wave, lane);

    // last-block-done: fence-free (v stores are device-coherent + vmcnt drained)
    asm volatile("s_waitcnt vmcnt(0)" ::: "memory");
    __syncthreads();
    if (t == 0) {
        unsigned int old = atomicAdd(donecnt, 1u);
        winner = (old == 255u) ? 1 : 0;
    }
    __syncthreads();
    if (!winner) return;

    // ---- 256-thread Aitken + softmax epilogue: zM = zb2, zM1 = zb1, zM2 = zb0 ----
    const float* zM  = zb2;
    const float* zM1 = zb1;
    const float* zM2 = zb0;
    float av[4], d1v[4];
    float s12 = 0.f, s22 = 0.f;
    #pragma unroll
    for (int k = 0; k < 4; ++k) {
        const int e = t + 256 * k;
        av[k] = zM[e];
        float bb = zM1[e], cc = zM2[e];
        d1v[k] = av[k] - bb;
        float d2 = bb - cc;
        s12 += d1v[k] * d2;
        s22 += d2 * d2;
    }
    #pragma unroll
    for (int off = 32; off >= 1; off >>= 1) s12 += __shfl_down(s12, off, 64);
    if (lane == 0) red4[wave] = s12;
    __syncthreads();
    if (t == 0) bvalS = red4[0] + red4[1] + red4[2] + red4[3];
    __syncthreads();
    const float dot12 = bvalS;
    __syncthreads();
    #pragma unroll
    for (int off = 32; off >= 1; off >>= 1) s22 += __shfl_down(s22, off, 64);
    if (lane == 0) red4[wave] = s22;
    __syncthreads();
    if (t == 0) bvalS = red4[0] + red4[1] + red4[2] + red4[3];
    __syncthreads();
    const float dot22 = bvalS;
    __syncthreads();

    float lam = dot12 / fmaxf(dot22, 1e-30f);
    lam = fminf(fmaxf(lam, 0.0f), 0.95f);
    const float coef = lam / (1.0f - lam);
    #pragma unroll
    for (int k = 0; k < 4; ++k) ush[t + 256 * k] = av[k] + coef * d1v[k];
    __syncthreads();

    float Pv[4];
    float ps = 0.f;
    #pragma unroll
    for (int k = 0; k < 4; ++k) {
        const int e = t + 256 * k;
        Pv[k] = (e >= 1) ? 0.1f * ush[e] : 0.f;
        ps += Pv[k];
    }
    #pragma unroll
    for (int off = 32; off >= 1; off >>= 1) ps += __shfl_down(ps, off, 64);
    if (lane == 0) red4[wave] = ps;
    __syncthreads();
    if (t == 0) bvalS = (red4[0] + red4[1] + red4[2] + red4[3]) / 1023.0f;
    __syncthreads();
    const float mean = bvalS;
    __syncthreads();

    float mx = 0.f;   // relu'd values >= 0
    #pragma unroll
    for (int k = 0; k < 4; ++k) {
        const int e = t + 256 * k;
        if (e >= 1) {
            Pv[k] = fmaxf(Pv[k] - mean, 0.f) * 100.f;
            mx = fmaxf(mx, Pv[k]);
        }
    }
    #pragma unroll
    for (int off = 32; off >= 1; off >>= 1) mx = fmaxf(mx, __shfl_down(mx, off, 64));
    if (lane == 0) red4[wave] = mx;
    __syncthreads();
    if (t == 0) bvalS = fmaxf(fmaxf(red4[0], red4[1]), fmaxf(red4[2], red4[3]));
    __syncthreads();
    const float gmax = bvalS;
    __syncthreads();

    float Ev[4];
    float es = 0.f;
    #pragma unroll
    for (int k = 0; k < 4; ++k) {
        const int e = t + 256 * k;
        Ev[k] = (e >= 1) ? expf(Pv[k] - gmax) : 0.f;
        es += Ev[k];
    }
    #pragma unroll
    for (int off = 32; off >= 1; off >>= 1) es += __shfl_down(es, off, 64);
    if (lane == 0) red4[wave] = es;
    __syncthreads();
    if (t == 0) bvalS = red4[0] + red4[1] + red4[2] + red4[3];
    __syncthreads();
    const float esum = bvalS;
    #pragma unroll
    for (int k = 0; k < 4; ++k) {
        const int e = t + 256 * k;
        if (e >= 1) out[e - 1] = Ev[k] / esum;
    }
}

extern "C" void kernel_launch(void* const* d_in, const int* in_sizes, int n_in,
                              void* d_out, int out_size, void* d_ws, size_t ws_size,
                              hipStream_t stream) {
    const float* f  = (const float*)d_in[0];
    const float* w1 = (const float*)d_in[1];
    const float* b1 = (const float*)d_in[2];
    const float* w2 = (const float*)d_in[3];
    const float* b2 = (const float*)d_in[4];
    const float* w3 = (const float*)d_in[5];
    const float* b3 = (const float*)d_in[6];
    const float* w4 = (const float*)d_in[7];
    const float* b4 = (const float*)d_in[8];
    float* ws = (float*)d_ws;

    // Only the barrier + done counters need external zeroing (monotonic counters
    // cannot self-zero across graph replays; workspace is re-poisoned each iter).
    // fn2/mag/total are zeroed in-kernel by stage-A idle blocks.
    (void)hipMemsetAsync((char*)d_ws + 36096 * 4, 0, 8, stream);

    k_mega<<<256, 256, 0, stream>>>(f, w1, b1, w2, b2, w3, b3, w4, b4,
                                    ws, (float*)d_out);
}